// Round 1
// baseline (942.307 us; speedup 1.0000x reference)
//
#include <hip/hip_runtime.h>

#define N_NODES 2048
#define EDGES   65536

typedef __bf16 bf16x8 __attribute__((ext_vector_type(8)));
typedef float  f32x4  __attribute__((ext_vector_type(4)));

__device__ __forceinline__ unsigned short f2bf(float f) {
  unsigned u = __builtin_bit_cast(unsigned, f);
  unsigned r = u + 0x7FFFu + ((u >> 16) & 1u);
  return (unsigned short)(r >> 16);
}
__device__ __forceinline__ float bf2f(unsigned short h) {
  return __builtin_bit_cast(float, (unsigned)h << 16);
}
__device__ __forceinline__ void split1(float f, unsigned short& hi, unsigned short& lo) {
  hi = f2bf(f);
  lo = f2bf(f - bf2f(hi));
}

// ---------------- prep kernels ----------------
__global__ void k_deg(const int* __restrict__ ei, const float* __restrict__ ew,
                      float* __restrict__ deg) {
  int e = blockIdx.x * 256 + threadIdx.x;
  atomicAdd(&deg[ei[e]], ew[e]);
}
__global__ void k_dis(const float* __restrict__ deg, float* __restrict__ dis) {
  int n = blockIdx.x * 256 + threadIdx.x;
  float d = deg[n];
  dis[n] = d > 0.f ? 1.f / sqrtf(d) : 0.f;
}
__global__ void k_scatterS(const int* __restrict__ ei, const float* __restrict__ ew,
                           const float* __restrict__ dis, float* __restrict__ S) {
  int e = blockIdx.x * 256 + threadIdx.x;
  int r = ei[e], c = ei[EDGES + e];
  float w = -dis[r] * ew[e] * dis[c];
  atomicAdd(&S[c * N_NODES + r], w);
}
__global__ void k_bsum(const float* __restrict__ b, float* __restrict__ bs) {
  int t = blockIdx.x * 256 + threadIdx.x;   // 4096 threads
  int i = t >> 11, g = t & 2047;
  bs[t] = b[(i * 2 + 0) * 2048 + g] + b[(i * 2 + 1) * 2048 + g];
}

// ---------------- split-bf16 MFMA GEMM ----------------
// C[M=2048][N=4096] = act(A @ B + bias)
// MODE 0: A = S (lda 2048), B = x as (2048 x 4096) row-major, C = Tx1 (f32)
// MODE 1: A = [x | Tx1] (lda 4096 each half), B = W block-mapped, +bias, ReLU
template <int MODE>
__global__ __launch_bounds__(256, 2)
void gemm_split(const float* __restrict__ A0, const float* __restrict__ A1,
                const float* __restrict__ Bsrc, const float* __restrict__ bias,
                float* __restrict__ Cout, int Kdim) {
  // LDS: [row(128)][k(32)] bf16, 64B rows, XOR-swizzled 16B chunks
  __shared__ unsigned short As_hi[128 * 32];
  __shared__ unsigned short As_lo[128 * 32];
  __shared__ unsigned short Bs_hi[128 * 32];
  __shared__ unsigned short Bs_lo[128 * 32];

  const int tid  = threadIdx.x;
  const int lane = tid & 63;
  const int wid  = tid >> 6;
  const int wr   = wid >> 1, wc = wid & 1;
  const int n0   = blockIdx.x * 128;
  const int m0   = blockIdx.y * 128;

  const int lda = (MODE == 0) ? 2048 : 4096;
  const int ldb = (MODE == 0) ? 4096 : 2048;

  // staging maps
  const int a_m  = tid >> 3;        // +32 per phase
  const int a_k4 = tid & 7;         // k = 4*a_k4
  const int b_n4 = tid & 31;        // n = 4*b_n4 + c
  const int b_kg = tid >> 5;        // k = 4*b_kg

  // A write byte offset (phase 0); +2048 per phase. swizzle bits: (m&3)
  const int awb = a_m * 64 + (((8 * a_k4) & 48) ^ ((a_m & 3) << 4)) + ((8 * a_k4) & 8);
  // B write byte offset (c=0); +64 per c. swizzle bits: (n>>2)&3 == b_n4&3
  const int bwb = (4 * b_n4) * 64 + (((8 * b_kg) & 48) ^ ((b_n4 & 3) << 4)) + ((8 * b_kg) & 8);

  // frag read byte offsets
  int arb[4], brb[4];
#pragma unroll
  for (int mf = 0; mf < 4; ++mf) {
    int row = wr * 64 + mf * 16 + (lane & 15);
    arb[mf] = row * 64 + ((((lane >> 4) << 4)) ^ ((lane & 3) << 4));
  }
#pragma unroll
  for (int nf = 0; nf < 4; ++nf) {
    int row = wc * 64 + nf * 16 + (lane & 15);
    brb[nf] = row * 64 + ((((lane >> 4) << 4)) ^ (((lane >> 2) & 3) << 4));
  }

  f32x4 acc[4][4] = {};

  for (int k0 = 0; k0 < Kdim; k0 += 32) {
    const float* Ab;
    if (MODE == 0) Ab = A0 + k0;
    else           Ab = (k0 < 4096) ? (A0 + k0) : (A1 + (k0 - 4096));
    const float* Bb;
    if (MODE == 0) {
      Bb = Bsrc + (size_t)k0 * 4096 + n0;
    } else {
      int kjb = k0 >> 11;
      int ii  = n0 >> 11;
      int f0  = k0 & 2047, g0 = n0 & 2047;
      int jj  = kjb & 1, kc = kjb >> 1;
      Bb = Bsrc + ((size_t)((ii * 2 + jj) * 2 + kc) << 22) + (size_t)f0 * 2048 + g0;
    }

    __syncthreads();   // previous tile's compute done before overwrite

    // ---- stage A (128x32 f32 -> hi/lo bf16), conflict-free b64 writes ----
#pragma unroll
    for (int p = 0; p < 4; ++p) {
      int m = a_m + p * 32;
      const float4 v = *(const float4*)(Ab + (size_t)(m0 + m) * lda + a_k4 * 4);
      ushort4 hi, lo;
      split1(v.x, hi.x, lo.x);
      split1(v.y, hi.y, lo.y);
      split1(v.z, hi.z, lo.z);
      split1(v.w, hi.w, lo.w);
      int byte = awb + p * 2048;
      *(ushort4*)((char*)As_hi + byte) = hi;
      *(ushort4*)((char*)As_lo + byte) = lo;
    }

    // ---- stage B (32x128 f32, register 4x4 transpose -> [n][k]) ----
    {
      const float* bp = Bb + (size_t)(b_kg * 4) * ldb + b_n4 * 4;
      const float4 r0 = *(const float4*)(bp);
      const float4 r1 = *(const float4*)(bp + ldb);
      const float4 r2 = *(const float4*)(bp + 2 * (size_t)ldb);
      const float4 r3 = *(const float4*)(bp + 3 * (size_t)ldb);
      const float c0[4] = {r0.x, r1.x, r2.x, r3.x};
      const float c1[4] = {r0.y, r1.y, r2.y, r3.y};
      const float c2[4] = {r0.z, r1.z, r2.z, r3.z};
      const float c3[4] = {r0.w, r1.w, r2.w, r3.w};
      const float* cols[4] = {c0, c1, c2, c3};
#pragma unroll
      for (int c = 0; c < 4; ++c) {
        ushort4 hi, lo;
        split1(cols[c][0], hi.x, lo.x);
        split1(cols[c][1], hi.y, lo.y);
        split1(cols[c][2], hi.z, lo.z);
        split1(cols[c][3], hi.w, lo.w);
        int byte = bwb + c * 64;
        *(ushort4*)((char*)Bs_hi + byte) = hi;
        *(ushort4*)((char*)Bs_lo + byte) = lo;
      }
    }

    __syncthreads();

    // ---- fragments + 3-term split MFMA ----
    bf16x8 ah[4], al[4], bh[4], bl[4];
#pragma unroll
    for (int mf = 0; mf < 4; ++mf) {
      ah[mf] = *(const bf16x8*)((const char*)As_hi + arb[mf]);
      al[mf] = *(const bf16x8*)((const char*)As_lo + arb[mf]);
    }
#pragma unroll
    for (int nf = 0; nf < 4; ++nf) {
      bh[nf] = *(const bf16x8*)((const char*)Bs_hi + brb[nf]);
      bl[nf] = *(const bf16x8*)((const char*)Bs_lo + brb[nf]);
    }
#pragma unroll
    for (int mf = 0; mf < 4; ++mf) {
#pragma unroll
      for (int nf = 0; nf < 4; ++nf) {
        acc[mf][nf] = __builtin_amdgcn_mfma_f32_16x16x32_bf16(ah[mf], bh[nf], acc[mf][nf], 0, 0, 0);
        acc[mf][nf] = __builtin_amdgcn_mfma_f32_16x16x32_bf16(ah[mf], bl[nf], acc[mf][nf], 0, 0, 0);
        acc[mf][nf] = __builtin_amdgcn_mfma_f32_16x16x32_bf16(al[mf], bh[nf], acc[mf][nf], 0, 0, 0);
      }
    }
  }

  // ---- epilogue: C/D layout col = lane&15, row = (lane>>4)*4 + r ----
#pragma unroll
  for (int mf = 0; mf < 4; ++mf) {
#pragma unroll
    for (int nf = 0; nf < 4; ++nf) {
      int col = n0 + wc * 64 + nf * 16 + (lane & 15);
      float bv = (MODE == 1) ? bias[col] : 0.f;
#pragma unroll
      for (int r = 0; r < 4; ++r) {
        int row = m0 + wr * 64 + mf * 16 + ((lane >> 4) * 4) + r;
        float v = acc[mf][nf][r] + bv;
        if (MODE == 1) v = fmaxf(v, 0.f);
        Cout[(size_t)row * 4096 + col] = v;
      }
    }
  }
}

// ---------------- launch ----------------
extern "C" void kernel_launch(void* const* d_in, const int* in_sizes, int n_in,
                              void* d_out, int out_size, void* d_ws, size_t ws_size,
                              hipStream_t stream) {
  const float* x  = (const float*)d_in[0];
  const int*   ei = (const int*)d_in[1];
  const float* ew = (const float*)d_in[2];
  const float* W  = (const float*)d_in[3];
  const float* b  = (const float*)d_in[4];
  float* out = (float*)d_out;

  char* ws = (char*)d_ws;
  float* S    = (float*)(ws);                         // 2048*2048*4 = 16777216 B
  float* deg  = (float*)(ws + 16777216);              // 8192 B
  float* dis  = (float*)(ws + 16785408);              // 8192 B
  float* bsum = (float*)(ws + 16793600);              // 16384 B
  float* Tx1  = (float*)(ws + 16809984);              // 2048*4096*4 = 33554432 B
  // total ws use: 50364416 B (~48 MB)

  // zero S + deg in one shot (contiguous)
  hipMemsetAsync(S, 0, 16785408, stream);

  k_deg<<<EDGES / 256, 256, 0, stream>>>(ei, ew, deg);
  k_dis<<<N_NODES / 256, 256, 0, stream>>>(deg, dis);
  k_scatterS<<<EDGES / 256, 256, 0, stream>>>(ei, ew, dis, S);
  k_bsum<<<4096 / 256, 256, 0, stream>>>(b, bsum);

  dim3 grid(32, 16);   // 4096/128 n-tiles x 2048/128 m-tiles
  // Tx1 = S @ X
  gemm_split<0><<<grid, 256, 0, stream>>>(S, nullptr, x, nullptr, Tx1, 2048);
  // out = relu([x | Tx1] @ W' + bsum)
  gemm_split<1><<<grid, 256, 0, stream>>>(x, Tx1, W, bsum, out, 8192);
}

// Round 7
// 908.814 us; speedup vs baseline: 1.0369x; 1.0369x over previous
//
#include <hip/hip_runtime.h>

#define N_NODES 2048
#define EDGES   65536

typedef __bf16 bf16x8 __attribute__((ext_vector_type(8)));
typedef float  f32x4  __attribute__((ext_vector_type(4)));

typedef __attribute__((address_space(1))) const unsigned int gu32;
typedef __attribute__((address_space(3))) unsigned int lu32;

__device__ __forceinline__ void gll16(const void* g, void* l) {
  __builtin_amdgcn_global_load_lds((gu32*)g, (lu32*)l, 16, 0, 0);
}

__device__ __forceinline__ unsigned short f2bf(float f) {
  unsigned u = __builtin_bit_cast(unsigned, f);
  unsigned r = u + 0x7FFFu + ((u >> 16) & 1u);
  return (unsigned short)(r >> 16);
}
__device__ __forceinline__ float bf2f(unsigned short h) {
  return __builtin_bit_cast(float, (unsigned)h << 16);
}
__device__ __forceinline__ void split1(float f, unsigned short& hi, unsigned short& lo) {
  hi = f2bf(f);
  lo = f2bf(f - bf2f(hi));
}

// ---------------- prep kernels ----------------
__global__ void k_deg(const int* __restrict__ ei, const float* __restrict__ ew,
                      float* __restrict__ deg) {
  int e = blockIdx.x * 256 + threadIdx.x;
  atomicAdd(&deg[ei[e]], ew[e]);
}
__global__ void k_dis(const float* __restrict__ deg, float* __restrict__ dis) {
  int n = blockIdx.x * 256 + threadIdx.x;
  float d = deg[n];
  dis[n] = d > 0.f ? 1.f / sqrtf(d) : 0.f;
}
__global__ void k_scatterS(const int* __restrict__ ei, const float* __restrict__ ew,
                           const float* __restrict__ dis, float* __restrict__ S) {
  int e = blockIdx.x * 256 + threadIdx.x;
  int r = ei[e], c = ei[EDGES + e];
  float w = -dis[r] * ew[e] * dis[c];
  atomicAdd(&S[c * N_NODES + r], w);
}
__global__ void k_bsum(const float* __restrict__ b, float* __restrict__ bs) {
  int t = blockIdx.x * 256 + threadIdx.x;   // 4096 threads
  int i = t >> 11, g = t & 2047;
  bs[t] = b[(i * 2 + 0) * 2048 + g] + b[(i * 2 + 1) * 2048 + g];
}

// split f32 -> bf16 hi/lo, same layout, vectorized x4
__global__ void k_split(const float* __restrict__ in, unsigned short* __restrict__ hi,
                        unsigned short* __restrict__ lo) {
  int t = blockIdx.x * 256 + threadIdx.x;
  float4 v = ((const float4*)in)[t];
  ushort4 h, l;
  split1(v.x, h.x, l.x);
  split1(v.y, h.y, l.y);
  split1(v.z, h.z, l.z);
  split1(v.w, h.w, l.w);
  ((ushort4*)hi)[t] = h;
  ((ushort4*)lo)[t] = l;
}

// transpose 64x64 tiles + split to bf16 hi/lo.
// WMODE 0: x (2048x4096, stride 4096) -> xT (4096x2048, stride 2048)
// WMODE 1: per-z W block (2048x2048) -> Wt rows g, cols f with out stride 8192
template <int WMODE>
__global__ void k_tsplit(const float* __restrict__ in, unsigned short* __restrict__ oh,
                         unsigned short* __restrict__ ol) {
  __shared__ float tl[64][65];
  const int tid = threadIdx.x;
  int in_stride, out_stride;
  size_t in_base, out_base;
  if (WMODE == 0) {
    in_stride = 4096; out_stride = 2048; in_base = 0; out_base = 0;
  } else {
    in_stride = 2048; out_stride = 8192;
    int z = blockIdx.z;                  // z = (i*2+j)*2+k
    int i = z >> 2, j = (z >> 1) & 1, k = z & 1;
    in_base = (size_t)z << 22;           // z * 2048*2048
    out_base = (size_t)i * 2048 * 8192 + (size_t)(k * 2 + j) * 2048;
  }
  const int r0 = blockIdx.y * 64, c0 = blockIdx.x * 64;

#pragma unroll
  for (int q = 0; q < 4; ++q) {
    int s = q * 256 + tid;
    int row = s >> 4, c4 = (s & 15) * 4;
    float4 v = *(const float4*)(in + in_base + (size_t)(r0 + row) * in_stride + c0 + c4);
    tl[row][c4 + 0] = v.x; tl[row][c4 + 1] = v.y;
    tl[row][c4 + 2] = v.z; tl[row][c4 + 3] = v.w;
  }
  __syncthreads();
#pragma unroll
  for (int q = 0; q < 4; ++q) {
    int s = q * 256 + tid;
    int cc = s >> 4, rr = (s & 15) * 4;
    ushort4 h, l;
    split1(tl[rr + 0][cc], h.x, l.x);
    split1(tl[rr + 1][cc], h.y, l.y);
    split1(tl[rr + 2][cc], h.z, l.z);
    split1(tl[rr + 3][cc], h.w, l.w);
    size_t o = out_base + (size_t)(c0 + cc) * out_stride + r0 + rr;
    *(ushort4*)(oh + o) = h;
    *(ushort4*)(ol + o) = l;
  }
}

// ---------------- pure-bf16 split MFMA GEMM (m97 structure) ----------------
// C[2048][4096] = act(A @ B^T + bias); A,B pre-packed bf16 hi/lo, rows x k linear.
// MODE 0: A = S_hi/lo (lda 2048), B = xT_hi/lo (ldb 2048), K=2048, out -> Tx1 hi/lo
// MODE 1: A = [x | Tx1] hi/lo (lda 4096), B = Wt_hi/lo (ldb 8192), K=8192, out fp32+bias+relu
template <int MODE>
__global__ __launch_bounds__(256, 2)
void gemm_bf16(const unsigned short* __restrict__ Ah0, const unsigned short* __restrict__ Al0,
               const unsigned short* __restrict__ Ah1, const unsigned short* __restrict__ Al1,
               const unsigned short* __restrict__ Bh, const unsigned short* __restrict__ Bl,
               const float* __restrict__ bias,
               float* __restrict__ outF, unsigned short* __restrict__ outH,
               unsigned short* __restrict__ outL, int Kdim) {
  // 4 tiles of [128 rows][32 k] bf16: Ah, Al, Bh, Bl = 32 KB
  __shared__ unsigned short lds[4 * 4096];

  const int tid  = threadIdx.x;
  const int lane = tid & 63;
  const int wid  = tid >> 6;
  const int wr   = wid >> 1, wc = wid & 1;

  // T1: bijective XCD-chunked block swizzle (nwg = 512, 512 % 8 == 0)
  const int flat = blockIdx.y * 32 + blockIdx.x;
  const int swz  = (flat & 7) * 64 + (flat >> 3);
  const int n0   = (swz & 31) * 128;
  const int m0   = (swz >> 5) * 128;

  const int ldab = ((MODE == 0) ? 2048 : 4096) * 2;  // bytes
  const int ldbb = ((MODE == 0) ? 2048 : 8192) * 2;  // bytes

  // staging: wave wid stages chunks c = wid*2 + q (q=0,1); each chunk = 16 rows.
  // lane l = 4r+pc: row = c*16 + r, phys k-chunk pc holds logical pc ^ ((r>>1)&3)
  const int srow = wid * 32 + (lane >> 2);
  const int kcl  = ((lane & 3) ^ ((lane >> 3) & 3)) * 16;  // byte offset in row
  const size_t rowA = (size_t)(m0 + srow) * ldab + kcl;
  const size_t rowB = (size_t)(n0 + srow) * ldbb + kcl;
  const int ldsc = wid * 2048;  // wave's chunk-pair base (bytes) within a tile

  // fragment read byte offsets (within a tile): row*64 + phys_chunk*16
  int arb[4], brb[4];
  const int physr = ((lane >> 4) ^ ((lane >> 1) & 3)) * 16;
#pragma unroll
  for (int mf = 0; mf < 4; ++mf)
    arb[mf] = (wr * 64 + mf * 16 + (lane & 15)) * 64 + physr;
#pragma unroll
  for (int nf = 0; nf < 4; ++nf)
    brb[nf] = (wc * 64 + nf * 16 + (lane & 15)) * 64 + physr;

  char* ldsb = (char*)lds;

  f32x4 acc[4][4] = {};

  for (int k0 = 0; k0 < Kdim; k0 += 32) {
    const char* bAh;
    const char* bAl;
    int kk = k0;
    if (MODE == 1 && k0 >= 4096) {
      bAh = (const char*)Ah1; bAl = (const char*)Al1; kk = k0 - 4096;
    } else {
      bAh = (const char*)Ah0; bAl = (const char*)Al0;
    }
    const size_t ka = rowA + (size_t)kk * 2;
    const size_t kb = rowB + (size_t)k0 * 2;
    const char* bBh = (const char*)Bh;
    const char* bBl = (const char*)Bl;

    __syncthreads();  // previous tile's compute done before overwrite
#pragma unroll
    for (int q = 0; q < 2; ++q) {
      const size_t ra = ka + (size_t)q * 16 * ldab;
      const size_t rb = kb + (size_t)q * 16 * ldbb;
      const int dst = ldsc + q * 1024;
      gll16(bAh + ra, ldsb + 0 * 8192 + dst);
      gll16(bAl + ra, ldsb + 1 * 8192 + dst);
      gll16(bBh + rb, ldsb + 2 * 8192 + dst);
      gll16(bBl + rb, ldsb + 3 * 8192 + dst);
    }
    __syncthreads();

    bf16x8 ah[4], al[4], bh[4], bl[4];
#pragma unroll
    for (int mf = 0; mf < 4; ++mf) {
      ah[mf] = *(const bf16x8*)(ldsb + 0 * 8192 + arb[mf]);
      al[mf] = *(const bf16x8*)(ldsb + 1 * 8192 + arb[mf]);
    }
#pragma unroll
    for (int nf = 0; nf < 4; ++nf) {
      bh[nf] = *(const bf16x8*)(ldsb + 2 * 8192 + brb[nf]);
      bl[nf] = *(const bf16x8*)(ldsb + 3 * 8192 + brb[nf]);
    }
#pragma unroll
    for (int mf = 0; mf < 4; ++mf) {
#pragma unroll
      for (int nf = 0; nf < 4; ++nf) {
        acc[mf][nf] = __builtin_amdgcn_mfma_f32_16x16x32_bf16(ah[mf], bh[nf], acc[mf][nf], 0, 0, 0);
        acc[mf][nf] = __builtin_amdgcn_mfma_f32_16x16x32_bf16(ah[mf], bl[nf], acc[mf][nf], 0, 0, 0);
        acc[mf][nf] = __builtin_amdgcn_mfma_f32_16x16x32_bf16(al[mf], bh[nf], acc[mf][nf], 0, 0, 0);
      }
    }
  }

  // epilogue: C/D layout col = lane&15, row = (lane>>4)*4 + r
#pragma unroll
  for (int mf = 0; mf < 4; ++mf) {
#pragma unroll
    for (int nf = 0; nf < 4; ++nf) {
      int col = n0 + wc * 64 + nf * 16 + (lane & 15);
      float bv = (MODE == 1) ? bias[col] : 0.f;
#pragma unroll
      for (int r = 0; r < 4; ++r) {
        int row = m0 + wr * 64 + mf * 16 + ((lane >> 4) * 4) + r;
        size_t o = (size_t)row * 4096 + col;
        float v = acc[mf][nf][r];
        if (MODE == 1) {
          outF[o] = fmaxf(v + bv, 0.f);
        } else {
          unsigned short h, l;
          split1(v, h, l);
          outH[o] = h;
          outL[o] = l;
        }
      }
    }
  }
}

// ---------------- launch ----------------
extern "C" void kernel_launch(void* const* d_in, const int* in_sizes, int n_in,
                              void* d_out, int out_size, void* d_ws, size_t ws_size,
                              hipStream_t stream) {
  const float* x  = (const float*)d_in[0];
  const int*   ei = (const int*)d_in[1];
  const float* ew = (const float*)d_in[2];
  const float* W  = (const float*)d_in[3];
  const float* b  = (const float*)d_in[4];
  float* out = (float*)d_out;

  // Workspace layout with liveness overlay (total 201,359,360 B ~= 192 MB):
  // [0, 67108864): region R, two uses in sequence:
  //   phase 1 (until gemm0 done): S fp32 | xT_hi | xT_lo | S_hi | S_lo
  //   phase 2 (k_tsplit<1> onward): Wt_hi [4096][8192]
  char* ws = (char*)d_ws;
  float*          S     = (float*)(ws + 0);                  // 16,777,216
  unsigned short* xT_hi = (unsigned short*)(ws + 16777216);  // 16,777,216
  unsigned short* xT_lo = (unsigned short*)(ws + 33554432);  // 16,777,216
  unsigned short* S_hi  = (unsigned short*)(ws + 50331648);  //  8,388,608
  unsigned short* S_lo  = (unsigned short*)(ws + 58720256);  //  8,388,608
  unsigned short* Wt_hi = (unsigned short*)(ws + 0);         // 67,108,864 (overlay)
  unsigned short* Wt_lo = (unsigned short*)(ws + 67108864);  // 67,108,864
  unsigned short* x_hi  = (unsigned short*)(ws + 134217728); // 16,777,216
  unsigned short* x_lo  = (unsigned short*)(ws + 150994944); // 16,777,216
  unsigned short* T_hi  = (unsigned short*)(ws + 167772160); // 16,777,216
  unsigned short* T_lo  = (unsigned short*)(ws + 184549376); // 16,777,216
  float*          deg   = (float*)(ws + 201326592);          //      8,192
  float*          dis   = (float*)(ws + 201334784);          //      8,192
  float*          bsum  = (float*)(ws + 201342976);          //     16,384

  hipMemsetAsync(S, 0, 16777216, stream);
  hipMemsetAsync(deg, 0, 8192, stream);

  k_deg<<<EDGES / 256, 256, 0, stream>>>(ei, ew, deg);
  k_dis<<<N_NODES / 256, 256, 0, stream>>>(deg, dis);
  k_scatterS<<<EDGES / 256, 256, 0, stream>>>(ei, ew, dis, S);
  k_bsum<<<4096 / 256, 256, 0, stream>>>(b, bsum);

  // pre-pack bf16 hi/lo operands for phase 1
  k_split<<<2097152 / 256, 256, 0, stream>>>(x, x_hi, x_lo);            // x rows
  k_split<<<1048576 / 256, 256, 0, stream>>>(S, S_hi, S_lo);            // S rows
  k_tsplit<0><<<dim3(64, 32, 1), 256, 0, stream>>>(x, xT_hi, xT_lo);    // x^T

  dim3 grid(32, 16);
  // Tx1 = S @ x  (writes bf16 hi/lo directly)
  gemm_bf16<0><<<grid, 256, 0, stream>>>(S_hi, S_lo, nullptr, nullptr,
                                         xT_hi, xT_lo, nullptr,
                                         nullptr, T_hi, T_lo, 2048);

  // W^T blocks — AFTER gemm0 so Wt_hi may overlay {S, xT, S_hi/lo} (now dead)
  k_tsplit<1><<<dim3(32, 32, 8), 256, 0, stream>>>(W, Wt_hi, Wt_lo);

  // out = relu([x | Tx1] @ Wt^T + bsum)
  gemm_bf16<1><<<grid, 256, 0, stream>>>(x_hi, x_lo, T_hi, T_lo,
                                         Wt_hi, Wt_lo, bsum,
                                         out, nullptr, nullptr, 8192);
}

// Round 9
// 821.786 us; speedup vs baseline: 1.1467x; 1.1059x over previous
//
#include <hip/hip_runtime.h>

#define N_NODES 2048
#define EDGES   65536

typedef __bf16 bf16x8 __attribute__((ext_vector_type(8)));
typedef float  f32x4  __attribute__((ext_vector_type(4)));

typedef __attribute__((address_space(1))) const unsigned int gu32;
typedef __attribute__((address_space(3))) unsigned int lu32;

__device__ __forceinline__ void gll16(const void* g, void* l) {
  __builtin_amdgcn_global_load_lds((gu32*)g, (lu32*)l, 16, 0, 0);
}

__device__ __forceinline__ unsigned short f2bf(float f) {
  unsigned u = __builtin_bit_cast(unsigned, f);
  unsigned r = u + 0x7FFFu + ((u >> 16) & 1u);
  return (unsigned short)(r >> 16);
}
__device__ __forceinline__ float bf2f(unsigned short h) {
  return __builtin_bit_cast(float, (unsigned)h << 16);
}
__device__ __forceinline__ void split1(float f, unsigned short& hi, unsigned short& lo) {
  hi = f2bf(f);
  lo = f2bf(f - bf2f(hi));
}

// ---------------- prep kernels ----------------
__global__ void k_deg(const int* __restrict__ ei, const float* __restrict__ ew,
                      float* __restrict__ deg) {
  int e = blockIdx.x * 256 + threadIdx.x;
  atomicAdd(&deg[ei[e]], ew[e]);
}
__global__ void k_dis(const float* __restrict__ deg, float* __restrict__ dis) {
  int n = blockIdx.x * 256 + threadIdx.x;
  float d = deg[n];
  dis[n] = d > 0.f ? 1.f / sqrtf(d) : 0.f;
}
__global__ void k_scatterS(const int* __restrict__ ei, const float* __restrict__ ew,
                           const float* __restrict__ dis, float* __restrict__ S) {
  int e = blockIdx.x * 256 + threadIdx.x;
  int r = ei[e], c = ei[EDGES + e];
  float w = -dis[r] * ew[e] * dis[c];
  atomicAdd(&S[c * N_NODES + r], w);
}
__global__ void k_bsum(const float* __restrict__ b, float* __restrict__ bs) {
  int t = blockIdx.x * 256 + threadIdx.x;   // 4096 threads
  int i = t >> 11, g = t & 2047;
  bs[t] = b[(i * 2 + 0) * 2048 + g] + b[(i * 2 + 1) * 2048 + g];
}

// split f32 -> bf16 hi/lo, same layout, vectorized x4
__global__ void k_split(const float* __restrict__ in, unsigned short* __restrict__ hi,
                        unsigned short* __restrict__ lo) {
  int t = blockIdx.x * 256 + threadIdx.x;
  float4 v = ((const float4*)in)[t];
  ushort4 h, l;
  split1(v.x, h.x, l.x);
  split1(v.y, h.y, l.y);
  split1(v.z, h.z, l.z);
  split1(v.w, h.w, l.w);
  ((ushort4*)hi)[t] = h;
  ((ushort4*)lo)[t] = l;
}

// transpose 64x64 tiles + split to bf16 hi/lo.
// WMODE 0: x (2048x4096, stride 4096) -> xT (4096x2048, stride 2048)
// WMODE 1: per-z W block (2048x2048) -> Wt rows g, cols f with out stride 8192
template <int WMODE>
__global__ void k_tsplit(const float* __restrict__ in, unsigned short* __restrict__ oh,
                         unsigned short* __restrict__ ol) {
  __shared__ float tl[64][65];
  const int tid = threadIdx.x;
  int in_stride, out_stride;
  size_t in_base, out_base;
  if (WMODE == 0) {
    in_stride = 4096; out_stride = 2048; in_base = 0; out_base = 0;
  } else {
    in_stride = 2048; out_stride = 8192;
    int z = blockIdx.z;                  // z = (i*2+j)*2+k
    int i = z >> 2, j = (z >> 1) & 1, k = z & 1;
    in_base = (size_t)z << 22;           // z * 2048*2048
    out_base = (size_t)i * 2048 * 8192 + (size_t)(k * 2 + j) * 2048;
  }
  const int r0 = blockIdx.y * 64, c0 = blockIdx.x * 64;

#pragma unroll
  for (int q = 0; q < 4; ++q) {
    int s = q * 256 + tid;
    int row = s >> 4, c4 = (s & 15) * 4;
    float4 v = *(const float4*)(in + in_base + (size_t)(r0 + row) * in_stride + c0 + c4);
    tl[row][c4 + 0] = v.x; tl[row][c4 + 1] = v.y;
    tl[row][c4 + 2] = v.z; tl[row][c4 + 3] = v.w;
  }
  __syncthreads();
#pragma unroll
  for (int q = 0; q < 4; ++q) {
    int s = q * 256 + tid;
    int cc = s >> 4, rr = (s & 15) * 4;
    ushort4 h, l;
    split1(tl[rr + 0][cc], h.x, l.x);
    split1(tl[rr + 1][cc], h.y, l.y);
    split1(tl[rr + 2][cc], h.z, l.z);
    split1(tl[rr + 3][cc], h.w, l.w);
    size_t o = out_base + (size_t)(c0 + cc) * out_stride + r0 + rr;
    *(ushort4*)(oh + o) = h;
    *(ushort4*)(ol + o) = l;
  }
}

// ---------------- split-bf16 MFMA GEMM, 256x128 tile, dbuf + counted waits ----
// C[2048][4096] = act(A @ B^T + bias); A,B pre-packed bf16 hi/lo, rows x k linear.
// MODE 0: A = S_hi/lo (lda 2048), B = xT_hi/lo (ldb 2048), K=2048, out -> Tx1 hi/lo
// MODE 1: A = [x | Tx1] hi/lo (lda 4096), B = Wt_hi/lo (ldb 8192), K=8192, out fp32+bias+relu
// 512 threads (8 waves: wr=wid>>1 in 0..3 m-quadrant, wc=wid&1 n-half).
// LDS per half: Ah[256][32] @0, Al @16384, Bh[128][32] @32768, Bl @40960 (48 KB); 2 halves.
template <int MODE>
__global__ __launch_bounds__(512, 1)
void gemm_bf16(const unsigned short* __restrict__ Ah0, const unsigned short* __restrict__ Al0,
               const unsigned short* __restrict__ Ah1, const unsigned short* __restrict__ Al1,
               const unsigned short* __restrict__ Bh, const unsigned short* __restrict__ Bl,
               const float* __restrict__ bias,
               float* __restrict__ outF, unsigned short* __restrict__ outH,
               unsigned short* __restrict__ outL, int Kdim) {
  __shared__ alignas(16) char lds[2 * 49152];

  const int tid  = threadIdx.x;
  const int lane = tid & 63;
  const int wid  = tid >> 6;         // 0..7
  const int wr   = wid >> 1;         // 0..3
  const int wc   = wid & 1;          // 0..1

  // T1: bijective XCD-chunked swizzle; 256 wgs, one m-stripe per XCD
  const int flat = blockIdx.y * 32 + blockIdx.x;     // grid (32, 8)
  const int swz  = (flat & 7) * 32 + (flat >> 3);
  const int n0   = (swz & 31) * 128;
  const int m0   = (swz >> 5) * 256;

  const int ldab = ((MODE == 0) ? 2048 : 4096) * 2;  // bytes
  const int ldbb = ((MODE == 0) ? 2048 : 8192) * 2;  // bytes

  // staging maps: chunk = 16 rows, lane l: row=c*16+(l>>2), phys k-chunk l&3
  // holds logical (l&3)^((r>>1)&3)  [XOR swizzle via pre-swizzled global src]
  const int rsub = lane >> 2;
  const int kcl  = ((lane & 3) ^ ((lane >> 3) & 3)) * 16;
  const size_t arow0 = (size_t)(m0 + wid * 32 + rsub) * ldab + kcl;       // A chunk 2w
  const size_t arow1 = (size_t)(m0 + wid * 32 + 16 + rsub) * ldab + kcl;  // A chunk 2w+1
  const size_t brow  = (size_t)(n0 + wid * 16 + rsub) * ldbb + kcl;       // B chunk w

  // fragment read byte offsets: row*64 + phys_chunk*16 (matches write involution)
  int arb[4], brb[4];
  const int physr = ((lane >> 4) ^ ((lane >> 1) & 3)) * 16;
#pragma unroll
  for (int mf = 0; mf < 4; ++mf)
    arb[mf] = (wr * 64 + mf * 16 + (lane & 15)) * 64 + physr;
#pragma unroll
  for (int nf = 0; nf < 4; ++nf)
    brb[nf] = (wc * 64 + nf * 16 + (lane & 15)) * 64 + physr;

  auto STAGE = [&](int half, int k0) {
    const char* pAh;
    const char* pAl;
    size_t ka;
    if (MODE == 1 && k0 >= 4096) {
      pAh = (const char*)Ah1; pAl = (const char*)Al1; ka = (size_t)(k0 - 4096) * 2;
    } else {
      pAh = (const char*)Ah0; pAl = (const char*)Al0; ka = (size_t)k0 * 2;
    }
    const size_t kb = (size_t)k0 * 2;
    char* base = lds + half * 49152;
    gll16(pAh + arow0 + ka, base + 0     + (2 * wid + 0) * 1024);
    gll16(pAh + arow1 + ka, base + 0     + (2 * wid + 1) * 1024);
    gll16(pAl + arow0 + ka, base + 16384 + (2 * wid + 0) * 1024);
    gll16(pAl + arow1 + ka, base + 16384 + (2 * wid + 1) * 1024);
    gll16((const char*)Bh + brow + kb, base + 32768 + wid * 1024);
    gll16((const char*)Bl + brow + kb, base + 40960 + wid * 1024);
  };

  f32x4 acc[4][4] = {};
  const int nt = Kdim / 32;

  // prologue
  STAGE(0, 0);
  asm volatile("s_waitcnt vmcnt(0)" ::: "memory");
  __builtin_amdgcn_s_barrier();

  int cur = 0;
  for (int t = 0; t < nt; ++t) {
    if (t + 1 < nt) STAGE(cur ^ 1, (t + 1) * 32);   // prefetch issues first

    const char* base = lds + cur * 49152;
    bf16x8 ah[4], al[4], bh[4], bl[4];
#pragma unroll
    for (int mf = 0; mf < 4; ++mf) {
      ah[mf] = *(const bf16x8*)(base + arb[mf]);
      al[mf] = *(const bf16x8*)(base + 16384 + arb[mf]);
    }
#pragma unroll
    for (int nf = 0; nf < 4; ++nf) {
      bh[nf] = *(const bf16x8*)(base + 32768 + brb[nf]);
      bl[nf] = *(const bf16x8*)(base + 40960 + brb[nf]);
    }
    asm volatile("s_waitcnt lgkmcnt(0)" ::: "memory");
    __builtin_amdgcn_sched_barrier(0);              // rule #18: pin MFMA below wait

    __builtin_amdgcn_s_setprio(1);
#pragma unroll
    for (int mf = 0; mf < 4; ++mf) {
#pragma unroll
      for (int nf = 0; nf < 4; ++nf) {
        acc[mf][nf] = __builtin_amdgcn_mfma_f32_16x16x32_bf16(ah[mf], bh[nf], acc[mf][nf], 0, 0, 0);
        acc[mf][nf] = __builtin_amdgcn_mfma_f32_16x16x32_bf16(ah[mf], bl[nf], acc[mf][nf], 0, 0, 0);
        acc[mf][nf] = __builtin_amdgcn_mfma_f32_16x16x32_bf16(al[mf], bh[nf], acc[mf][nf], 0, 0, 0);
      }
    }
    __builtin_amdgcn_s_setprio(0);

    asm volatile("s_waitcnt vmcnt(0)" ::: "memory"); // prefetch landed (had MFMA to hide)
    __builtin_amdgcn_s_barrier();
    cur ^= 1;
  }

  // epilogue: C/D layout col = lane&15, row = (lane>>4)*4 + r
#pragma unroll
  for (int mf = 0; mf < 4; ++mf) {
#pragma unroll
    for (int nf = 0; nf < 4; ++nf) {
      int col = n0 + wc * 64 + nf * 16 + (lane & 15);
      float bv = (MODE == 1) ? bias[col] : 0.f;
#pragma unroll
      for (int r = 0; r < 4; ++r) {
        int row = m0 + wr * 64 + mf * 16 + ((lane >> 4) * 4) + r;
        size_t o = (size_t)row * 4096 + col;
        float v = acc[mf][nf][r];
        if (MODE == 1) {
          outF[o] = fmaxf(v + bv, 0.f);
        } else {
          unsigned short h, l;
          split1(v, h, l);
          outH[o] = h;
          outL[o] = l;
        }
      }
    }
  }
}

// ---------------- launch ----------------
extern "C" void kernel_launch(void* const* d_in, const int* in_sizes, int n_in,
                              void* d_out, int out_size, void* d_ws, size_t ws_size,
                              hipStream_t stream) {
  const float* x  = (const float*)d_in[0];
  const int*   ei = (const int*)d_in[1];
  const float* ew = (const float*)d_in[2];
  const float* W  = (const float*)d_in[3];
  const float* b  = (const float*)d_in[4];
  float* out = (float*)d_out;

  // Workspace layout with liveness overlay (total ~192 MB):
  // [0, 67108864): phase 1: S fp32 | xT_hi | xT_lo | S_hi | S_lo
  //                phase 2 (k_tsplit<1> onward): Wt_hi [4096][8192]
  char* ws = (char*)d_ws;
  float*          S     = (float*)(ws + 0);                  // 16,777,216
  unsigned short* xT_hi = (unsigned short*)(ws + 16777216);  // 16,777,216
  unsigned short* xT_lo = (unsigned short*)(ws + 33554432);  // 16,777,216
  unsigned short* S_hi  = (unsigned short*)(ws + 50331648);  //  8,388,608
  unsigned short* S_lo  = (unsigned short*)(ws + 58720256);  //  8,388,608
  unsigned short* Wt_hi = (unsigned short*)(ws + 0);         // 67,108,864 (overlay)
  unsigned short* Wt_lo = (unsigned short*)(ws + 67108864);  // 67,108,864
  unsigned short* x_hi  = (unsigned short*)(ws + 134217728); // 16,777,216
  unsigned short* x_lo  = (unsigned short*)(ws + 150994944); // 16,777,216
  unsigned short* T_hi  = (unsigned short*)(ws + 167772160); // 16,777,216
  unsigned short* T_lo  = (unsigned short*)(ws + 184549376); // 16,777,216
  float*          deg   = (float*)(ws + 201326592);          //      8,192
  float*          dis   = (float*)(ws + 201334784);          //      8,192
  float*          bsum  = (float*)(ws + 201342976);          //     16,384

  hipMemsetAsync(S, 0, 16777216, stream);
  hipMemsetAsync(deg, 0, 8192, stream);

  k_deg<<<EDGES / 256, 256, 0, stream>>>(ei, ew, deg);
  k_dis<<<N_NODES / 256, 256, 0, stream>>>(deg, dis);
  k_scatterS<<<EDGES / 256, 256, 0, stream>>>(ei, ew, dis, S);
  k_bsum<<<4096 / 256, 256, 0, stream>>>(b, bsum);

  // pre-pack bf16 hi/lo operands for phase 1
  k_split<<<2097152 / 256, 256, 0, stream>>>(x, x_hi, x_lo);            // x rows
  k_split<<<1048576 / 256, 256, 0, stream>>>(S, S_hi, S_lo);            // S rows
  k_tsplit<0><<<dim3(64, 32, 1), 256, 0, stream>>>(x, xT_hi, xT_lo);    // x^T

  dim3 grid(32, 8);   // 32 n-tiles x 8 m-tiles (BM=256, BN=128), 256 wgs
  // Tx1 = S @ x  (writes bf16 hi/lo directly)
  gemm_bf16<0><<<grid, 512, 0, stream>>>(S_hi, S_lo, nullptr, nullptr,
                                         xT_hi, xT_lo, nullptr,
                                         nullptr, T_hi, T_lo, 2048);

  // W^T blocks — AFTER gemm0 so Wt_hi may overlay {S, xT, S_hi/lo} (now dead)
  k_tsplit<1><<<dim3(32, 32, 8), 256, 0, stream>>>(W, Wt_hi, Wt_lo);

  // out = relu([x | Tx1] @ Wt^T + bsum)
  gemm_bf16<1><<<grid, 512, 0, stream>>>(x_hi, x_lo, T_hi, T_lo,
                                         Wt_hi, Wt_lo, bsum,
                                         out, nullptr, nullptr, 8192);
}

// Round 12
// 796.625 us; speedup vs baseline: 1.1829x; 1.0316x over previous
//
#include <hip/hip_runtime.h>

#define N_NODES 2048
#define EDGES   65536

typedef __bf16 bf16x8 __attribute__((ext_vector_type(8)));
typedef float  f32x4  __attribute__((ext_vector_type(4)));

typedef __attribute__((address_space(1))) const unsigned int gu32;
typedef __attribute__((address_space(3))) unsigned int lu32;

__device__ __forceinline__ void gll16(const void* g, void* l) {
  __builtin_amdgcn_global_load_lds((gu32*)g, (lu32*)l, 16, 0, 0);
}

__device__ __forceinline__ unsigned short f2bf(float f) {
  unsigned u = __builtin_bit_cast(unsigned, f);
  unsigned r = u + 0x7FFFu + ((u >> 16) & 1u);
  return (unsigned short)(r >> 16);
}
__device__ __forceinline__ float bf2f(unsigned short h) {
  return __builtin_bit_cast(float, (unsigned)h << 16);
}
__device__ __forceinline__ void split1(float f, unsigned short& hi, unsigned short& lo) {
  hi = f2bf(f);
  lo = f2bf(f - bf2f(hi));
}

// ---------------- prep kernels ----------------
__global__ void k_deg(const int* __restrict__ ei, const float* __restrict__ ew,
                      float* __restrict__ deg) {
  int e = blockIdx.x * 256 + threadIdx.x;
  atomicAdd(&deg[ei[e]], ew[e]);
}
__global__ void k_dis(const float* __restrict__ deg, float* __restrict__ dis) {
  int n = blockIdx.x * 256 + threadIdx.x;
  float d = deg[n];
  dis[n] = d > 0.f ? 1.f / sqrtf(d) : 0.f;
}
__global__ void k_scatterS(const int* __restrict__ ei, const float* __restrict__ ew,
                           const float* __restrict__ dis, float* __restrict__ S) {
  int e = blockIdx.x * 256 + threadIdx.x;
  int r = ei[e], c = ei[EDGES + e];
  float w = -dis[r] * ew[e] * dis[c];
  atomicAdd(&S[c * N_NODES + r], w);
}
__global__ void k_bsum(const float* __restrict__ b, float* __restrict__ bs) {
  int t = blockIdx.x * 256 + threadIdx.x;   // 4096 threads
  int i = t >> 11, g = t & 2047;
  bs[t] = b[(i * 2 + 0) * 2048 + g] + b[(i * 2 + 1) * 2048 + g];
}

// split f32 -> bf16 hi/lo, same layout, vectorized x4
__global__ void k_split(const float* __restrict__ in, unsigned short* __restrict__ hi,
                        unsigned short* __restrict__ lo) {
  int t = blockIdx.x * 256 + threadIdx.x;
  float4 v = ((const float4*)in)[t];
  ushort4 h, l;
  split1(v.x, h.x, l.x);
  split1(v.y, h.y, l.y);
  split1(v.z, h.z, l.z);
  split1(v.w, h.w, l.w);
  ((ushort4*)hi)[t] = h;
  ((ushort4*)lo)[t] = l;
}

// transpose 64x64 tiles + split to bf16 hi/lo.
// WMODE 0: x (2048x4096, stride 4096) -> xT (4096x2048, stride 2048)
// WMODE 1: per-z W block (2048x2048) -> Wt rows g, cols f with out stride 8192
template <int WMODE>
__global__ void k_tsplit(const float* __restrict__ in, unsigned short* __restrict__ oh,
                         unsigned short* __restrict__ ol) {
  __shared__ float tl[64][65];
  const int tid = threadIdx.x;
  int in_stride, out_stride;
  size_t in_base, out_base;
  if (WMODE == 0) {
    in_stride = 4096; out_stride = 2048; in_base = 0; out_base = 0;
  } else {
    in_stride = 2048; out_stride = 8192;
    int z = blockIdx.z;                  // z = (i*2+j)*2+k
    int i = z >> 2, j = (z >> 1) & 1, k = z & 1;
    in_base = (size_t)z << 22;           // z * 2048*2048
    out_base = (size_t)i * 2048 * 8192 + (size_t)(k * 2 + j) * 2048;
  }
  const int r0 = blockIdx.y * 64, c0 = blockIdx.x * 64;

#pragma unroll
  for (int q = 0; q < 4; ++q) {
    int s = q * 256 + tid;
    int row = s >> 4, c4 = (s & 15) * 4;
    float4 v = *(const float4*)(in + in_base + (size_t)(r0 + row) * in_stride + c0 + c4);
    tl[row][c4 + 0] = v.x; tl[row][c4 + 1] = v.y;
    tl[row][c4 + 2] = v.z; tl[row][c4 + 3] = v.w;
  }
  __syncthreads();
#pragma unroll
  for (int q = 0; q < 4; ++q) {
    int s = q * 256 + tid;
    int cc = s >> 4, rr = (s & 15) * 4;
    ushort4 h, l;
    split1(tl[rr + 0][cc], h.x, l.x);
    split1(tl[rr + 1][cc], h.y, l.y);
    split1(tl[rr + 2][cc], h.z, l.z);
    split1(tl[rr + 3][cc], h.w, l.w);
    size_t o = out_base + (size_t)(c0 + cc) * out_stride + r0 + rr;
    *(ushort4*)(oh + o) = h;
    *(ushort4*)(ol + o) = l;
  }
}

// ---- split-bf16 MFMA GEMM, 256x128 tile, 3-buf pipeline, counted vmcnt ----
// C[2048][4096] = act(A @ B^T + bias); A,B pre-packed bf16 hi/lo, rows x k linear.
// MODE 0: A = S_hi/lo (lda 2048), B = xT_hi/lo (ldb 2048), K=2048, out -> Tx1 hi/lo
// MODE 1: A = [x | Tx1] hi/lo (lda 4096), B = Wt_hi/lo (ldb 8192), K=8192, out fp32+bias+relu
// 512 threads (8 waves). LDS buffer (48 KB): Ah[256][32] @0, Al @16384,
// Bh[128][32] @32768, Bl @40960; 3 buffers (144 KB), 2-deep prefetch.
template <int MODE>
__global__ __launch_bounds__(512, 1)
void gemm_bf16(const unsigned short* __restrict__ Ah0, const unsigned short* __restrict__ Al0,
               const unsigned short* __restrict__ Ah1, const unsigned short* __restrict__ Al1,
               const unsigned short* __restrict__ Bh, const unsigned short* __restrict__ Bl,
               const float* __restrict__ bias,
               float* __restrict__ outF, unsigned short* __restrict__ outH,
               unsigned short* __restrict__ outL, int Kdim) {
  __shared__ alignas(16) char lds[3 * 49152];

  const int tid  = threadIdx.x;
  const int lane = tid & 63;
  const int wid  = tid >> 6;         // 0..7
  const int wr   = wid >> 1;         // 0..3
  const int wc   = wid & 1;          // 0..1

  // T1: bijective XCD-chunked swizzle; 256 wgs, one m-stripe per XCD
  const int flat = blockIdx.y * 32 + blockIdx.x;     // grid (32, 8)
  const int swz  = (flat & 7) * 32 + (flat >> 3);
  const int n0   = (swz & 31) * 128;
  const int m0   = (swz >> 5) * 256;

  const int ldab = ((MODE == 0) ? 2048 : 4096) * 2;  // bytes
  const int ldbb = ((MODE == 0) ? 2048 : 8192) * 2;  // bytes

  // staging maps: chunk = 16 rows, lane l: row=c*16+(l>>2), phys k-chunk l&3
  // holds logical (l&3)^((r>>1)&3)  [XOR swizzle via pre-swizzled global src]
  const int rsub = lane >> 2;
  const int kcl  = ((lane & 3) ^ ((lane >> 3) & 3)) * 16;
  const size_t arow0 = (size_t)(m0 + wid * 32 + rsub) * ldab + kcl;       // A chunk 2w
  const size_t arow1 = (size_t)(m0 + wid * 32 + 16 + rsub) * ldab + kcl;  // A chunk 2w+1
  const size_t brow  = (size_t)(n0 + wid * 16 + rsub) * ldbb + kcl;       // B chunk w

  // fragment read byte offsets: row*64 + phys_chunk*16 (matches write involution)
  int arb[4], brb[4];
  const int physr = ((lane >> 4) ^ ((lane >> 1) & 3)) * 16;
#pragma unroll
  for (int mf = 0; mf < 4; ++mf)
    arb[mf] = (wr * 64 + mf * 16 + (lane & 15)) * 64 + physr;
#pragma unroll
  for (int nf = 0; nf < 4; ++nf)
    brb[nf] = (wc * 64 + nf * 16 + (lane & 15)) * 64 + physr;

  auto STAGE = [&](char* base, int k0) {
    const char* pAh;
    const char* pAl;
    size_t ka;
    if (MODE == 1 && k0 >= 4096) {
      pAh = (const char*)Ah1; pAl = (const char*)Al1; ka = (size_t)(k0 - 4096) * 2;
    } else {
      pAh = (const char*)Ah0; pAl = (const char*)Al0; ka = (size_t)k0 * 2;
    }
    const size_t kb = (size_t)k0 * 2;
    gll16(pAh + arow0 + ka, base + 0     + (2 * wid + 0) * 1024);
    gll16(pAh + arow1 + ka, base + 0     + (2 * wid + 1) * 1024);
    gll16(pAl + arow0 + ka, base + 16384 + (2 * wid + 0) * 1024);
    gll16(pAl + arow1 + ka, base + 16384 + (2 * wid + 1) * 1024);
    gll16((const char*)Bh + brow + kb, base + 32768 + wid * 1024);
    gll16((const char*)Bl + brow + kb, base + 40960 + wid * 1024);
  };

  f32x4 acc[4][4] = {};
  const int nt = Kdim / 32;

  char* buf0 = lds;                // tile t
  char* buf1 = lds + 49152;        // tile t+1
  char* buf2 = lds + 2 * 49152;    // tile t+2 (stage target)

  // prologue: 2-deep prefetch (12 loads in flight per wave)
  STAGE(buf0, 0);
  STAGE(buf1, 32);

  for (int t = 0; t < nt; ++t) {
    // own tile-t loads done (6 newest = tile t+1 may remain in flight)
    if (t + 1 < nt) {
      asm volatile("s_waitcnt vmcnt(6)" ::: "memory");
    } else {
      asm volatile("s_waitcnt vmcnt(0)" ::: "memory");
    }
    // all waves' tile-t loads landed; all tile-(t-1) ds_reads retired
    __builtin_amdgcn_s_barrier();

    if (t + 2 < nt) STAGE(buf2, (t + 2) * 32);   // overwrites buf of t-1: safe

    bf16x8 ah[4], al[4], bh[4], bl[4];
#pragma unroll
    for (int mf = 0; mf < 4; ++mf) {
      ah[mf] = *(const bf16x8*)(buf0 + arb[mf]);
      al[mf] = *(const bf16x8*)(buf0 + 16384 + arb[mf]);
    }
#pragma unroll
    for (int nf = 0; nf < 4; ++nf) {
      bh[nf] = *(const bf16x8*)(buf0 + 32768 + brb[nf]);
      bl[nf] = *(const bf16x8*)(buf0 + 40960 + brb[nf]);
    }
    asm volatile("s_waitcnt lgkmcnt(0)" ::: "memory");
    __builtin_amdgcn_sched_barrier(0);           // rule #18: pin MFMA below wait

    __builtin_amdgcn_s_setprio(1);
#pragma unroll
    for (int mf = 0; mf < 4; ++mf) {
#pragma unroll
      for (int nf = 0; nf < 4; ++nf) {
        acc[mf][nf] = __builtin_amdgcn_mfma_f32_16x16x32_bf16(ah[mf], bh[nf], acc[mf][nf], 0, 0, 0);
        acc[mf][nf] = __builtin_amdgcn_mfma_f32_16x16x32_bf16(ah[mf], bl[nf], acc[mf][nf], 0, 0, 0);
        acc[mf][nf] = __builtin_amdgcn_mfma_f32_16x16x32_bf16(al[mf], bh[nf], acc[mf][nf], 0, 0, 0);
      }
    }
    __builtin_amdgcn_s_setprio(0);

    char* tmp = buf0; buf0 = buf1; buf1 = buf2; buf2 = tmp;   // rotate
  }

  // epilogue: C/D layout col = lane&15, row = (lane>>4)*4 + r
#pragma unroll
  for (int mf = 0; mf < 4; ++mf) {
#pragma unroll
    for (int nf = 0; nf < 4; ++nf) {
      int col = n0 + wc * 64 + nf * 16 + (lane & 15);
      float bv = (MODE == 1) ? bias[col] : 0.f;
#pragma unroll
      for (int r = 0; r < 4; ++r) {
        int row = m0 + wr * 64 + mf * 16 + ((lane >> 4) * 4) + r;
        size_t o = (size_t)row * 4096 + col;
        float v = acc[mf][nf][r];
        if (MODE == 1) {
          outF[o] = fmaxf(v + bv, 0.f);
        } else {
          unsigned short h, l;
          split1(v, h, l);
          outH[o] = h;
          outL[o] = l;
        }
      }
    }
  }
}

// ---------------- launch ----------------
extern "C" void kernel_launch(void* const* d_in, const int* in_sizes, int n_in,
                              void* d_out, int out_size, void* d_ws, size_t ws_size,
                              hipStream_t stream) {
  const float* x  = (const float*)d_in[0];
  const int*   ei = (const int*)d_in[1];
  const float* ew = (const float*)d_in[2];
  const float* W  = (const float*)d_in[3];
  const float* b  = (const float*)d_in[4];
  float* out = (float*)d_out;

  // Workspace layout with liveness overlay (total ~192 MB):
  // [0, 67108864): phase 1: S fp32 | xT_hi | xT_lo | S_hi | S_lo
  //                phase 2 (k_tsplit<1> onward): Wt_hi [4096][8192]
  char* ws = (char*)d_ws;
  float*          S     = (float*)(ws + 0);                  // 16,777,216
  unsigned short* xT_hi = (unsigned short*)(ws + 16777216);  // 16,777,216
  unsigned short* xT_lo = (unsigned short*)(ws + 33554432);  // 16,777,216
  unsigned short* S_hi  = (unsigned short*)(ws + 50331648);  //  8,388,608
  unsigned short* S_lo  = (unsigned short*)(ws + 58720256);  //  8,388,608
  unsigned short* Wt_hi = (unsigned short*)(ws + 0);         // 67,108,864 (overlay)
  unsigned short* Wt_lo = (unsigned short*)(ws + 67108864);  // 67,108,864
  unsigned short* x_hi  = (unsigned short*)(ws + 134217728); // 16,777,216
  unsigned short* x_lo  = (unsigned short*)(ws + 150994944); // 16,777,216
  unsigned short* T_hi  = (unsigned short*)(ws + 167772160); // 16,777,216
  unsigned short* T_lo  = (unsigned short*)(ws + 184549376); // 16,777,216
  float*          deg   = (float*)(ws + 201326592);          //      8,192
  float*          dis   = (float*)(ws + 201334784);          //      8,192
  float*          bsum  = (float*)(ws + 201342976);          //     16,384

  hipMemsetAsync(S, 0, 16777216, stream);
  hipMemsetAsync(deg, 0, 8192, stream);

  k_deg<<<EDGES / 256, 256, 0, stream>>>(ei, ew, deg);
  k_dis<<<N_NODES / 256, 256, 0, stream>>>(deg, dis);
  k_scatterS<<<EDGES / 256, 256, 0, stream>>>(ei, ew, dis, S);
  k_bsum<<<4096 / 256, 256, 0, stream>>>(b, bsum);

  // pre-pack bf16 hi/lo operands for phase 1
  k_split<<<2097152 / 256, 256, 0, stream>>>(x, x_hi, x_lo);            // x rows
  k_split<<<1048576 / 256, 256, 0, stream>>>(S, S_hi, S_lo);            // S rows
  k_tsplit<0><<<dim3(64, 32, 1), 256, 0, stream>>>(x, xT_hi, xT_lo);    // x^T

  dim3 grid(32, 8);   // 32 n-tiles x 8 m-tiles (BM=256, BN=128), 256 wgs
  // Tx1 = S @ x  (writes bf16 hi/lo directly)
  gemm_bf16<0><<<grid, 512, 0, stream>>>(S_hi, S_lo, nullptr, nullptr,
                                         xT_hi, xT_lo, nullptr,
                                         nullptr, T_hi, T_lo, 2048);

  // W^T blocks — AFTER gemm0 so Wt_hi may overlay {S, xT, S_hi/lo} (now dead)
  k_tsplit<1><<<dim3(32, 32, 8), 256, 0, stream>>>(W, Wt_hi, Wt_lo);

  // out = relu([x | Tx1] @ Wt^T + bsum)
  gemm_bf16<1><<<grid, 512, 0, stream>>>(x_hi, x_lo, T_hi, T_lo,
                                         Wt_hi, Wt_lo, bsum,
                                         out, nullptr, nullptr, 8192);
}